// Round 1
// baseline (27565.796 us; speedup 1.0000x reference)
//
#include <hip/hip_runtime.h>
#include <hip/hip_bf16.h>

// ContinuousThoughtMachineReLU  (B=32, C=512, N=1024, E=512, D=2048, H=8, hd=64,
//                                T=50, O=1000, NA=512, NO=512)
//
// Strategy (round 0 baseline):
//  - precompute: kv = LN(x^T @ W_kv + b_kv);  K,V = kv@{Wk_a,Wv_a} (bf16 stored)
//  - fold  W_qq  = W_q @ Wq_a   (qh = syncA @ W_qq + b_qq)
//  - fold  W_comb= W_ao @ W_syn[:E]  into W_full rows 0..511; W_syn[E:] rows 512..2559
//  - loop weights stored bf16; skinny GEMMs (M=32) use split-K + fp32 atomicAdd,
//    bias+ReLU deferred to consumers.

typedef unsigned short u16;

__device__ __forceinline__ float bf2f(u16 u) {
    return __uint_as_float(((unsigned int)u) << 16);
}
__device__ __forceinline__ float bflo(unsigned int u) { return __uint_as_float(u << 16); }
__device__ __forceinline__ float bfhi(unsigned int u) { return __uint_as_float(u & 0xffff0000u); }
__device__ __forceinline__ u16 f2bf(float f) {
    unsigned int u = __float_as_uint(f);
    unsigned int r = u + 0x7fffu + ((u >> 16) & 1u);
    return (u16)(r >> 16);
}

// ---------------------------------------------------------------- init
__global__ __launch_bounds__(256) void k_init(
    const float* __restrict__ start_state, const float* __restrict__ dec_a,
    const float* __restrict__ dec_o,
    float* act0, float* aA, float* bA, float* aO, float* bO,
    float* r_a, float* r_o)
{
    int g = blockIdx.x * 256 + threadIdx.x;
    int T = gridDim.x * 256;
    for (int i = g; i < 32 * 2048; i += T) act0[i] = start_state[i & 2047];
    for (int i = g; i < 32 * 512; i += T) { aA[i] = 0.f; bA[i] = 0.f; aO[i] = 0.f; bO[i] = 0.f; }
    for (int i = g; i < 512; i += T) {
        float da = fminf(fmaxf(dec_a[i], 0.f), 15.f);
        float dv = fminf(fmaxf(dec_o[i], 0.f), 15.f);
        r_a[i] = __expf(-da);
        r_o[i] = __expf(-dv);
    }
}

// ------------------------------------------------- kv = x^T @ W_kv + b_kv (fp32 out)
// grid (N/128=4, M/64=512), block 256.  rows r = b*1024+n ; A[r][c] = x[b][c][n]
__global__ __launch_bounds__(256) void k_gemm_xT(
    const float* __restrict__ x, const float* __restrict__ Wkv,
    const float* __restrict__ bkv, float* __restrict__ out)
{
    __shared__ float As[16 * 68];
    __shared__ float Bs[16 * 132];
    int tid = threadIdx.x;
    int tn = tid & 15, tm = tid >> 4;
    int n0 = blockIdx.x * 128;
    int r0 = blockIdx.y * 64;
    int b = r0 >> 10;
    int nrow0 = r0 & 1023;
    const float* xb = x + (size_t)b * 512 * 1024;
    float acc[4][8];
#pragma unroll
    for (int i = 0; i < 4; ++i)
#pragma unroll
        for (int j = 0; j < 8; ++j) acc[i][j] = 0.f;

    for (int k0 = 0; k0 < 512; k0 += 16) {
        __syncthreads();
#pragma unroll
        for (int l = 0; l < 4; ++l) {
            int i = tid + l * 256;
            int nn = i & 63, kk = i >> 6;
            As[kk * 68 + nn] = xb[(size_t)(k0 + kk) * 1024 + nrow0 + nn];
        }
#pragma unroll
        for (int l = 0; l < 8; ++l) {
            int i = tid + l * 256;
            int n = i & 127, kk = i >> 7;
            Bs[kk * 132 + n] = Wkv[(size_t)(k0 + kk) * 512 + n0 + n];
        }
        __syncthreads();
#pragma unroll
        for (int k = 0; k < 16; ++k) {
            float4 a4 = *(const float4*)&As[k * 68 + tm * 4];
            float4 b0 = *(const float4*)&Bs[k * 132 + tn * 8];
            float4 b1 = *(const float4*)&Bs[k * 132 + tn * 8 + 4];
            float av[4] = {a4.x, a4.y, a4.z, a4.w};
            float bv[8] = {b0.x, b0.y, b0.z, b0.w, b1.x, b1.y, b1.z, b1.w};
#pragma unroll
            for (int i = 0; i < 4; ++i)
#pragma unroll
                for (int j = 0; j < 8; ++j) acc[i][j] += av[i] * bv[j];
        }
    }
#pragma unroll
    for (int i = 0; i < 4; ++i) {
        int r = r0 + tm * 4 + i;
        int c = n0 + tn * 8;
        float* orow = out + (size_t)r * 512 + c;
#pragma unroll
        for (int j = 0; j < 8; ++j) orow[j] = acc[i][j] + bkv[c + j];
    }
}

// ------------------------------------------------ generic fp32 GEMM -> bf16 out, K=512
// out[r][n] = sum_k A[r*lda+k]*B[k*ldb+n] (+bias[n]);  grid (N/128, M/64)
__global__ __launch_bounds__(256) void k_gemm_AB(
    const float* __restrict__ A, int lda,
    const float* __restrict__ B, int ldb,
    const float* __restrict__ bias,
    u16* __restrict__ out, int N)
{
    __shared__ float As[16 * 68];
    __shared__ float Bs[16 * 132];
    int tid = threadIdx.x;
    int tn = tid & 15, tm = tid >> 4;
    int n0 = blockIdx.x * 128;
    int r0 = blockIdx.y * 64;
    float acc[4][8];
#pragma unroll
    for (int i = 0; i < 4; ++i)
#pragma unroll
        for (int j = 0; j < 8; ++j) acc[i][j] = 0.f;

    for (int k0 = 0; k0 < 512; k0 += 16) {
        __syncthreads();
#pragma unroll
        for (int l = 0; l < 4; ++l) {
            int i = tid + l * 256;
            int kk = i & 15, m = i >> 4;
            As[kk * 68 + m] = A[(size_t)(r0 + m) * lda + k0 + kk];
        }
#pragma unroll
        for (int l = 0; l < 8; ++l) {
            int i = tid + l * 256;
            int n = i & 127, kk = i >> 7;
            Bs[kk * 132 + n] = B[(size_t)(k0 + kk) * ldb + n0 + n];
        }
        __syncthreads();
#pragma unroll
        for (int k = 0; k < 16; ++k) {
            float4 a4 = *(const float4*)&As[k * 68 + tm * 4];
            float4 b0 = *(const float4*)&Bs[k * 132 + tn * 8];
            float4 b1 = *(const float4*)&Bs[k * 132 + tn * 8 + 4];
            float av[4] = {a4.x, a4.y, a4.z, a4.w};
            float bv[8] = {b0.x, b0.y, b0.z, b0.w, b1.x, b1.y, b1.z, b1.w};
#pragma unroll
            for (int i = 0; i < 4; ++i)
#pragma unroll
                for (int j = 0; j < 8; ++j) acc[i][j] += av[i] * bv[j];
        }
    }
#pragma unroll
    for (int i = 0; i < 4; ++i) {
        int r = r0 + tm * 4 + i;
        int c = n0 + tn * 8;
        float vv[8];
#pragma unroll
        for (int j = 0; j < 8; ++j) vv[j] = acc[i][j] + (bias ? bias[c + j] : 0.f);
        unsigned int w0 = (unsigned int)f2bf(vv[0]) | ((unsigned int)f2bf(vv[1]) << 16);
        unsigned int w1 = (unsigned int)f2bf(vv[2]) | ((unsigned int)f2bf(vv[3]) << 16);
        unsigned int w2 = (unsigned int)f2bf(vv[4]) | ((unsigned int)f2bf(vv[5]) << 16);
        unsigned int w3 = (unsigned int)f2bf(vv[6]) | ((unsigned int)f2bf(vv[7]) << 16);
        *(uint4*)&out[(size_t)r * N + c] = make_uint4(w0, w1, w2, w3);
    }
}

// ------------------------------------------------- in-place LN over kv rows (512 wide)
// grid 8192, block 256 (4 waves, 1 row/wave)
__global__ __launch_bounds__(256) void k_ln_kv(
    float* __restrict__ kv, const float* __restrict__ g, const float* __restrict__ be)
{
    int tid = threadIdx.x;
    int lane = tid & 63;
    int row = blockIdx.x * 4 + (tid >> 6);
    float* p = kv + (size_t)row * 512 + lane * 8;
    float4 u0 = *(float4*)p;
    float4 u1 = *(float4*)(p + 4);
    float v[8] = {u0.x, u0.y, u0.z, u0.w, u1.x, u1.y, u1.z, u1.w};
    float s = 0.f, s2 = 0.f;
#pragma unroll
    for (int i = 0; i < 8; ++i) { s += v[i]; s2 += v[i] * v[i]; }
#pragma unroll
    for (int off = 32; off >= 1; off >>= 1) {
        s += __shfl_xor(s, off, 64);
        s2 += __shfl_xor(s2, off, 64);
    }
    float m = s * (1.f / 512.f);
    float var = s2 * (1.f / 512.f) - m * m;
    float rs = rsqrtf(var + 1e-5f);
    const float* gp = g + lane * 8;
    const float* bp = be + lane * 8;
#pragma unroll
    for (int i = 0; i < 8; ++i) v[i] = (v[i] - m) * rs * gp[i] + bp[i];
    *(float4*)p = make_float4(v[0], v[1], v[2], v[3]);
    *(float4*)(p + 4) = make_float4(v[4], v[5], v[6], v[7]);
}

// ---------------------------------------------- bias-fold: out[j] = vin@B[:,j] + badd[j]
__global__ __launch_bounds__(256) void k_bvec(
    const float* __restrict__ vin, const float* __restrict__ B, int ldb,
    const float* __restrict__ badd, float* __restrict__ out, int Nj)
{
    int j = blockIdx.x * 256 + threadIdx.x;
    if (j >= Nj) return;
    float s = 0.f;
    for (int e = 0; e < 512; ++e) s += vin[e] * B[(size_t)e * ldb + j];
    out[j] = s + badd[j];
}

// ---------------------------------------------- f32 -> bf16 convert
__global__ __launch_bounds__(256) void k_convert(
    const float* __restrict__ src, u16* __restrict__ dst, int n)
{
    int g = blockIdx.x * 256 + threadIdx.x;
    int T = gridDim.x * 256;
    for (int i = g; i < n; i += T) dst[i] = f2bf(src[i]);
}

// ---------------------------------------------- per-step: zero scratch + syncA update
// grid 64, block 256 (16384 threads)
__global__ __launch_bounds__(256) void k_step_pre(
    const float* __restrict__ actcur, const float* __restrict__ b2, int apply_tf,
    const int* __restrict__ idx_action, const float* __restrict__ r_a,
    float* aA, float* bA, float* syncA,
    float* h_pre, float* t1_pre, float* actnext)
{
    int g = blockIdx.x * 256 + threadIdx.x;
    for (int i = g; i < 32 * 4096; i += 16384) h_pre[i] = 0.f;
    for (int i = g; i < 32 * 2048; i += 16384) { t1_pre[i] = 0.f; actnext[i] = 0.f; }
    int b = g >> 9, j = g & 511;
    int ia = idx_action[j];
    float v = actcur[b * 2048 + ia];
    if (apply_tf) v = fmaxf(0.f, v + b2[ia]);
    float r = r_a[j];
    float a = r * aA[g] + v * v;
    float bb = r * bA[g] + 1.f;
    aA[g] = a; bA[g] = bb;
    syncA[g] = a * rsqrtf(bb);
}

// ---------------------------------------------- fused qh + attention, one block per (b,h)
// grid 256, block 256
__global__ __launch_bounds__(256) void k_attn(
    const float* __restrict__ syncA, const u16* __restrict__ Wqq,
    const float* __restrict__ bqq, const u16* __restrict__ Kb,
    const u16* __restrict__ Vb, float* __restrict__ attn)
{
    __shared__ float sA[512];
    __shared__ float qh[64];
    __shared__ float sc[1024];
    __shared__ float red[256];
    int tid = threadIdx.x;
    int b = blockIdx.x >> 3, h = blockIdx.x & 7;

    for (int i = tid; i < 512; i += 256) sA[i] = syncA[b * 512 + i];
    __syncthreads();

    // qh slice (64 outputs): d = tid&63, kg = tid>>6 over 4 chunks of 128
    {
        int d = tid & 63, kg = tid >> 6;
        const u16* wp = Wqq + (size_t)(kg * 128) * 512 + h * 64 + d;
        const float* ap = sA + kg * 128;
        float p = 0.f;
#pragma unroll 4
        for (int na = 0; na < 128; ++na) p += ap[na] * bf2f(wp[(size_t)na * 512]);
        red[tid] = p;
    }
    __syncthreads();
    if (tid < 64) qh[tid] = red[tid] + red[tid + 64] + red[tid + 128] + red[tid + 192] + bqq[h * 64 + tid];
    __syncthreads();

    // scores (4 rows of K per thread)
    const u16* Kbh = Kb + (size_t)b * 1024 * 512 + h * 64;
#pragma unroll
    for (int rr = 0; rr < 4; ++rr) {
        int n = rr * 256 + tid;
        const uint4* kp = (const uint4*)(Kbh + (size_t)n * 512);
        float dot = 0.f;
#pragma unroll
        for (int i = 0; i < 8; ++i) {
            uint4 u = kp[i];
            float4 q0 = *(float4*)&qh[i * 8];
            float4 q1 = *(float4*)&qh[i * 8 + 4];
            dot += q0.x * bflo(u.x) + q0.y * bfhi(u.x)
                 + q0.z * bflo(u.y) + q0.w * bfhi(u.y)
                 + q1.x * bflo(u.z) + q1.y * bfhi(u.z)
                 + q1.z * bflo(u.w) + q1.w * bfhi(u.w);
        }
        sc[n] = dot * 0.125f;  // 1/sqrt(64)
    }
    __syncthreads();

    // softmax: max
    float mx = fmaxf(fmaxf(sc[tid], sc[tid + 256]), fmaxf(sc[tid + 512], sc[tid + 768]));
    red[tid] = mx;
    __syncthreads();
    for (int s = 128; s > 0; s >>= 1) {
        if (tid < s) red[tid] = fmaxf(red[tid], red[tid + s]);
        __syncthreads();
    }
    float bmax = red[0];
    __syncthreads();
    // exp + sum
    float zs = 0.f;
#pragma unroll
    for (int rr = 0; rr < 4; ++rr) {
        int n = rr * 256 + tid;
        float e = __expf(sc[n] - bmax);
        sc[n] = e;
        zs += e;
    }
    red[tid] = zs;
    __syncthreads();
    for (int s = 128; s > 0; s >>= 1) {
        if (tid < s) red[tid] += red[tid + s];
        __syncthreads();
    }
    float Zinv = 1.f / red[0];
    __syncthreads();

    // attn = (w @ V) / Z :  d = tid&63, ng = tid>>6 over 4 n-ranges of 256
    {
        int d = tid & 63, ng = tid >> 6;
        const u16* Vbh = Vb + (size_t)b * 1024 * 512 + h * 64 + d;
        float acc = 0.f;
        int nb = ng * 256;
#pragma unroll 4
        for (int n = nb; n < nb + 256; ++n) acc += sc[n] * bf2f(Vbh[(size_t)n * 512]);
        red[tid] = acc;
    }
    __syncthreads();
    if (tid < 64) {
        float a = (red[tid] + red[tid + 64] + red[tid + 128] + red[tid + 192]) * Zinv;
        attn[b * 512 + h * 64 + tid] = a;
    }
}

// ---------------------------------------------- skinny GEMM (M=32), split-K atomics
// out[r][j] += sum_{k in split} Astage[r][k] * W[k][j]
// Astage = [A1 (opt bias+relu) | A2 (opt bias+relu)]
// grid (N/32, ksplit), block 256 = 32 j-lanes x 8 rowgroups(4 rows)
__global__ __launch_bounds__(256) void k_skinny(
    const float* __restrict__ A1, int K1, const float* __restrict__ tb1,
    const float* __restrict__ A2, int K2, const float* __restrict__ tb2,
    const u16* __restrict__ W, int N, int Ktot,
    float* __restrict__ out)
{
    __shared__ float Al[64 * 36];
    int tid = threadIdx.x;
    int jl = tid & 31, rg = tid >> 5;
    int j = blockIdx.x * 32 + jl;
    int krange = Ktot / gridDim.y;
    int kbeg = blockIdx.y * krange;
    float a0 = 0.f, a1 = 0.f, a2 = 0.f, a3 = 0.f;

    for (int k0 = kbeg; k0 < kbeg + krange; k0 += 64) {
        __syncthreads();
        for (int i = tid; i < 2048; i += 256) {
            int r = i >> 6, k = i & 63, kk = k0 + k;
            float v;
            if (kk < K1) {
                v = A1[r * K1 + kk];
                if (tb1) v = fmaxf(0.f, v + tb1[kk]);
            } else {
                int k2 = kk - K1;
                v = A2[r * K2 + k2];
                if (tb2) v = fmaxf(0.f, v + tb2[k2]);
            }
            Al[k * 36 + r] = v;
        }
        __syncthreads();
        const u16* wp = W + (size_t)k0 * N + j;
#pragma unroll 16
        for (int k = 0; k < 64; ++k) {
            float w = bf2f(wp[(size_t)k * N]);
            float4 a = *(const float4*)&Al[k * 36 + rg * 4];
            a0 += a.x * w; a1 += a.y * w; a2 += a.z * w; a3 += a.w * w;
        }
    }
    int r0 = rg * 4;
    atomicAdd(&out[(size_t)(r0 + 0) * N + j], a0);
    atomicAdd(&out[(size_t)(r0 + 1) * N + j], a1);
    atomicAdd(&out[(size_t)(r0 + 2) * N + j], a2);
    atomicAdd(&out[(size_t)(r0 + 3) * N + j], a3);
}

// ---------------------------------------------- GLU + double LayerNorm, block per b-row
__device__ __forceinline__ void blk_reduce2(float& s, float& s2, float* red, int tid)
{
#pragma unroll
    for (int off = 32; off >= 1; off >>= 1) {
        s += __shfl_xor(s, off, 64);
        s2 += __shfl_xor(s2, off, 64);
    }
    __syncthreads();
    if ((tid & 63) == 0) { red[(tid >> 6) * 2] = s; red[(tid >> 6) * 2 + 1] = s2; }
    __syncthreads();
    s = red[0] + red[2] + red[4] + red[6];
    s2 = red[1] + red[3] + red[5] + red[7];
    __syncthreads();
}

__global__ __launch_bounds__(256) void k_glu_ln(
    const float* __restrict__ h_pre, const float* __restrict__ bcomb,
    const float* __restrict__ gsyn, const float* __restrict__ besyn,
    const float* __restrict__ gpm, const float* __restrict__ bepm,
    float* __restrict__ hpm)
{
    __shared__ float red[8];
    int tid = threadIdx.x;
    int b = blockIdx.x;
    const float* hr = h_pre + (size_t)b * 4096;
    float zv[8];
    float s = 0.f, s2 = 0.f;
#pragma unroll
    for (int q = 0; q < 8; ++q) {
        int i = q * 256 + tid;
        float av = hr[i] + bcomb[i];
        float gv = hr[2048 + i] + bcomb[2048 + i];
        float z = av / (1.f + __expf(-gv));
        zv[q] = z; s += z; s2 += z * z;
    }
    blk_reduce2(s, s2, red, tid);
    float m1 = s * (1.f / 2048.f);
    float v1 = s2 * (1.f / 2048.f) - m1 * m1;
    float rs1 = rsqrtf(v1 + 1e-5f);
    float t = 0.f, t2 = 0.f;
#pragma unroll
    for (int q = 0; q < 8; ++q) {
        int i = q * 256 + tid;
        float st = (zv[q] - m1) * rs1 * gsyn[i] + besyn[i];
        zv[q] = st; t += st; t2 += st * st;
    }
    blk_reduce2(t, t2, red, tid);
    float m2 = t * (1.f / 2048.f);
    float v2 = t2 * (1.f / 2048.f) - m2 * m2;
    float rs2 = rsqrtf(v2 + 1e-5f);
#pragma unroll
    for (int q = 0; q < 8; ++q) {
        int i = q * 256 + tid;
        hpm[(size_t)b * 2048 + i] = (zv[q] - m2) * rs2 * gpm[i] + bepm[i];
    }
}

// ---------------------------------------------- syncO update (exactly once per (b,j))
// grid 64, block 256
__global__ __launch_bounds__(256) void k_syncO(
    const float* __restrict__ actnew, const float* __restrict__ b2,
    const int* __restrict__ idx_out, const float* __restrict__ r_o,
    float* aO, float* bO, float* syncO, float* outSync)
{
    int g = blockIdx.x * 256 + threadIdx.x;
    int b = g >> 9, j = g & 511;
    int io = idx_out[j];
    float v = fmaxf(0.f, actnew[b * 2048 + io] + b2[io]);
    float r = r_o[j];
    float a = r * aO[g] + v * v;
    float bb = r * bO[g] + 1.f;
    aO[g] = a; bO[g] = bb;
    float sy = a * rsqrtf(bb);
    syncO[g] = sy;
    if (outSync) outSync[g] = sy;
}

// ---------------------------------------------- pred = syncO @ W_out + b_out
// grid (4 jsplit of 250, 32 b), block 256
__global__ __launch_bounds__(256) void k_pred(
    const float* __restrict__ syncO, const u16* __restrict__ Wout,
    const float* __restrict__ bout, float* __restrict__ pred)
{
    __shared__ float sO[512];
    int tid = threadIdx.x;
    int b = blockIdx.y;
    int j0 = blockIdx.x * 250;
    for (int i = tid; i < 512; i += 256) sO[i] = syncO[b * 512 + i];
    __syncthreads();
    if (tid < 250) {
        int j = j0 + tid;
        float s = 0.f;
#pragma unroll 8
        for (int k = 0; k < 512; ++k) s += sO[k] * bf2f(Wout[(size_t)k * 1000 + j]);
        pred[b * 1000 + j] = s + bout[j];
    }
}

// ---------------------------------------------- log-softmax entropy + strided output writes
// grid 32, block 256
__global__ __launch_bounds__(256) void k_out(
    const float* __restrict__ pred, int t, float* __restrict__ dout)
{
    __shared__ float p[1000];
    __shared__ float red[4];
    int tid = threadIdx.x;
    int b = blockIdx.x;
    float mx = -1e30f;
    for (int i = tid; i < 1000; i += 256) {
        float v = pred[b * 1000 + i];
        p[i] = v;
        mx = fmaxf(mx, v);
    }
#pragma unroll
    for (int off = 32; off >= 1; off >>= 1) mx = fmaxf(mx, __shfl_xor(mx, off, 64));
    __syncthreads();
    if ((tid & 63) == 0) red[tid >> 6] = mx;
    __syncthreads();
    mx = fmaxf(fmaxf(red[0], red[1]), fmaxf(red[2], red[3]));
    float zs = 0.f;
    for (int i = tid; i < 1000; i += 256) zs += __expf(p[i] - mx);
#pragma unroll
    for (int off = 32; off >= 1; off >>= 1) zs += __shfl_xor(zs, off, 64);
    __syncthreads();
    if ((tid & 63) == 0) red[tid >> 6] = zs;
    __syncthreads();
    float Z = red[0] + red[1] + red[2] + red[3];
    float logZ = __logf(Z);
    float se = 0.f;
    for (int i = tid; i < 1000; i += 256) {
        float lp = p[i] - mx - logZ;
        se += __expf(lp) * lp;
    }
#pragma unroll
    for (int off = 32; off >= 1; off >>= 1) se += __shfl_xor(se, off, 64);
    __syncthreads();
    if ((tid & 63) == 0) red[tid >> 6] = se;
    __syncthreads();
    float S = red[0] + red[1] + red[2] + red[3];
    float ne = -S / logf(1000.0f);
    for (int i = tid; i < 1000; i += 256)
        dout[(size_t)b * 50000 + (size_t)i * 50 + t] = p[i];
    if (tid == 0) {
        dout[1600000 + b * 100 + t] = ne;
        dout[1600000 + b * 100 + 50 + t] = 1.f - ne;
    }
}

// ================================================================ host launcher
extern "C" void kernel_launch(void* const* d_in, const int* in_sizes, int n_in,
                              void* d_out, int out_size, void* d_ws, size_t ws_size,
                              hipStream_t stream)
{
    const float* x      = (const float*)d_in[0];
    const float* W_kv   = (const float*)d_in[1];
    const float* b_kv   = (const float*)d_in[2];
    const float* g_kv   = (const float*)d_in[3];
    const float* be_kv  = (const float*)d_in[4];
    const float* W_q    = (const float*)d_in[5];
    const float* b_q    = (const float*)d_in[6];
    const float* W_in   = (const float*)d_in[7];
    const float* b_in   = (const float*)d_in[8];
    const float* W_ao   = (const float*)d_in[9];
    const float* b_ao   = (const float*)d_in[10];
    const float* W_syn  = (const float*)d_in[11];
    const float* b_syn  = (const float*)d_in[12];
    const float* g_syn  = (const float*)d_in[13];
    const float* be_syn = (const float*)d_in[14];
    const float* g_pm   = (const float*)d_in[15];
    const float* be_pm  = (const float*)d_in[16];
    const float* W1     = (const float*)d_in[17];
    const float* b1     = (const float*)d_in[18];
    const float* W2     = (const float*)d_in[19];
    const float* b2     = (const float*)d_in[20];
    const float* start_state  = (const float*)d_in[21];
    const float* decay_action = (const float*)d_in[22];
    const float* decay_out    = (const float*)d_in[23];
    const float* W_out  = (const float*)d_in[24];
    const float* b_out  = (const float*)d_in[25];
    const int* idx_action = (const int*)d_in[26];
    const int* idx_out    = (const int*)d_in[27];
    float* out = (float*)d_out;

    char* ws = (char*)d_ws;
    size_t off = 0;
    auto take = [&](size_t bytes) -> char* {
        char* p = ws + off;
        off += (bytes + 255) & ~(size_t)255;
        return p;
    };

    // region0: kv (fp32, precompute-only), later aliased by loop weights
    char* region0 = take(67108864);                 // 32768*512*4
    float* kv = (float*)region0;
    u16* W_full = (u16*)region0;                    // 2560 x 4096 bf16 = 20,971,520
    u16* W1b    = (u16*)(region0 + 20971520);       // 8,388,608
    u16* W2b    = (u16*)(region0 + 29360128);       // 8,388,608
    u16* Woutb  = (u16*)(region0 + 37748736);       // 1,024,000
    u16* Wqqb   = (u16*)(region0 + 38772736);       // 524,288  (ends 39,297,024 < 64MB)

    u16* K_bf = (u16*)take(33554432);
    u16* V_bf = (u16*)take(33554432);
    float* b_qq   = (float*)take(2048);
    float* b_comb = (float*)take(16384);
    float* r_a = (float*)take(2048);
    float* r_o = (float*)take(2048);
    float* aA = (float*)take(65536);
    float* bA = (float*)take(65536);
    float* aO = (float*)take(65536);
    float* bO = (float*)take(65536);
    float* syncA = (float*)take(65536);
    float* syncO = (float*)take(65536);
    float* act0v = (float*)take(262144);
    float* act1v = (float*)take(262144);
    float* h_pre = (float*)take(524288);
    float* hpm   = (float*)take(262144);
    float* t1_pre = (float*)take(262144);
    float* attnb = (float*)take(65536);
    float* pred_buf = (float*)take(128000);
    (void)ws_size; (void)in_sizes; (void)n_in; (void)out_size;

    // ---------------- precompute ----------------
    k_init<<<256, 256, 0, stream>>>(start_state, decay_action, decay_out,
                                    act0v, aA, bA, aO, bO, r_a, r_o);
    k_gemm_xT<<<dim3(4, 512), 256, 0, stream>>>(x, W_kv, b_kv, kv);
    k_ln_kv<<<8192, 256, 0, stream>>>(kv, g_kv, be_kv);
    // K = kv @ Wk_a + bk_a ; V = kv @ Wv_a + bv_a   (Wk_a = W_in[:,512:1024] etc.)
    k_gemm_AB<<<dim3(4, 512), 256, 0, stream>>>(kv, 512, W_in + 512, 1536, b_in + 512, K_bf, 512);
    k_gemm_AB<<<dim3(4, 512), 256, 0, stream>>>(kv, 512, W_in + 1024, 1536, b_in + 1024, V_bf, 512);
    // kv now dead -> region0 reused for loop weights
    k_gemm_AB<<<dim3(4, 8), 256, 0, stream>>>(W_q, 512, W_in, 1536, nullptr, Wqqb, 512);
    k_gemm_AB<<<dim3(32, 8), 256, 0, stream>>>(W_ao, 512, W_syn, 4096, nullptr, W_full, 4096);
    k_bvec<<<2, 256, 0, stream>>>(b_q, W_in, 1536, b_in, b_qq, 512);
    k_bvec<<<16, 256, 0, stream>>>(b_ao, W_syn, 4096, b_syn, b_comb, 4096);
    k_convert<<<2048, 256, 0, stream>>>(W_syn + (size_t)512 * 4096, W_full + (size_t)512 * 4096, 2048 * 4096);
    k_convert<<<2048, 256, 0, stream>>>(W1, W1b, 2048 * 2048);
    k_convert<<<2048, 256, 0, stream>>>(W2, W2b, 2048 * 2048);
    k_convert<<<512, 256, 0, stream>>>(W_out, Woutb, 512 * 1000);

    // ---------------- recurrent loop ----------------
    for (int t = 0; t < 50; ++t) {
        float* actcur = (t & 1) ? act1v : act0v;
        float* actnext = (t & 1) ? act0v : act1v;
        k_step_pre<<<64, 256, 0, stream>>>(actcur, b2, t > 0 ? 1 : 0, idx_action, r_a,
                                           aA, bA, syncA, h_pre, t1_pre, actnext);
        k_attn<<<256, 256, 0, stream>>>(syncA, Wqqb, b_qq, K_bf, V_bf, attnb);
        // h_pre = attn @ W_full[0:512] + act @ W_full[512:2560]   (bias b_comb at consumer)
        k_skinny<<<dim3(128, 4), 256, 0, stream>>>(attnb, 512, nullptr,
                                                   actcur, 2048, (t > 0 ? b2 : nullptr),
                                                   W_full, 4096, 2560, h_pre);
        k_glu_ln<<<32, 256, 0, stream>>>(h_pre, b_comb, g_syn, be_syn, g_pm, be_pm, hpm);
        // t1_pre = hpm @ W1 (bias+relu at consumer)
        k_skinny<<<dim3(64, 4), 256, 0, stream>>>(hpm, 2048, nullptr,
                                                  nullptr, 0, nullptr,
                                                  W1b, 2048, 2048, t1_pre);
        // actnext = relu(t1_pre + b1) @ W2 (bias+relu at consumers)
        k_skinny<<<dim3(64, 4), 256, 0, stream>>>(t1_pre, 2048, b1,
                                                  nullptr, 0, nullptr,
                                                  W2b, 2048, 2048, actnext);
        k_syncO<<<64, 256, 0, stream>>>(actnext, b2, idx_out, r_o, aO, bO, syncO,
                                        (t == 49) ? (out + 1603200) : nullptr);
        k_pred<<<dim3(4, 32), 256, 0, stream>>>(syncO, Woutb, b_out, pred_buf);
        k_out<<<32, 256, 0, stream>>>(pred_buf, t, out);
    }
}